// Round 5
// baseline (3499.738 us; speedup 1.0000x reference)
//
#include <hip/hip_runtime.h>
#include <hip/hip_bf16.h>

// DecoderRNNsearch on MI355X — round 8: persistent cooperative recurrence with
// a hand-rolled, INVALIDATION-FREE grid barrier.
//   r5 failed because grid.sync()'s acquire fence invalidates all 8 XCD L2s ->
//   ctxW+Whh (28MB) refetched from HBM every step (FETCH 1.76GB, 343GB/s).
//   Fix: cooperative launch (co-residency) but custom barrier:
//     - arrive: __syncthreads (drains stores) + agent-scope fetch_add
//     - wait:   RELAXED agent atomic spin (NO acquire -> NO buffer_inv)
//     - all cross-barrier mutable data (hf, attn, ghG) via agent-scope
//       atomic load/store (sc0+sc1 -> LLC-coherent, never cached in L1/L2)
//     - read-only data (ctxW, Whh, ctxWc, gxe) via plain cached loads ->
//       stays L2-resident across all 64 steps.
//   Per step: phase1 = attn (blk 0-63) || gh (blk 64-255, 64j x 16b each,
//   XCD-aware mapping, h re-split to bf16 in LDS); barrier; phase2 = gate
//   (r7-verified 512-thr split-gather, fp32 ctxWc nontemporal); barrier.
// Numerics identical to the passing r7 kernel (fp32/split-bf16 only in loop).

using short8 = __attribute__((ext_vector_type(8))) short;
using f32x4  = __attribute__((ext_vector_type(4))) float;

#define FLAG_ACC 1
#define FLAG_BF  2

#define AL(p)    __hip_atomic_load((p), __ATOMIC_RELAXED, __HIP_MEMORY_SCOPE_AGENT)
#define AS(p, v) __hip_atomic_store((p), (v), __ATOMIC_RELAXED, __HIP_MEMORY_SCOPE_AGENT)

__device__ __forceinline__ void gld16(const void* g, void* l) {
  __builtin_amdgcn_global_load_lds(
      (const __attribute__((address_space(1))) unsigned int*)g,
      (__attribute__((address_space(3))) unsigned int*)l, 16, 0, 0);
}

// ---------------- conversion / prep kernels ----------------

__global__ __launch_bounds__(256) void split_bf16_kernel(
    const float* __restrict__ x, __hip_bfloat16* __restrict__ hi,
    __hip_bfloat16* __restrict__ lo, int n)
{
  int i = blockIdx.x * blockDim.x + threadIdx.x;
  int stride = gridDim.x * blockDim.x;
  for (; i < n; i += stride) {
    float v = x[i];
    __hip_bfloat16 h = __float2bfloat16(v);
    hi[i] = h;
    lo[i] = __float2bfloat16(v - __bfloat162float(h));
  }
}

// permute rows j' = 3u+g  <-  source row g*1024+u ; split to bf16 hi/lo
__global__ __launch_bounds__(256) void prep_weights(
    const float* __restrict__ Wih, const float* __restrict__ Whh,
    const float* __restrict__ bih, const float* __restrict__ bhh,
    __hip_bfloat16* __restrict__ WcH, __hip_bfloat16* __restrict__ WcL,
    __hip_bfloat16* __restrict__ We,
    __hip_bfloat16* __restrict__ WhH, __hip_bfloat16* __restrict__ WhL,
    float* __restrict__ bihp, float* __restrict__ bhhp)
{
  const int jp = blockIdx.x;           // 0..3071
  const int u = jp / 3, g = jp - 3 * u;
  const int src = g * 1024 + u;
  for (int c = threadIdx.x; c < 2048; c += 256) {
    float v = Wih[(size_t)src * 2560 + 512 + c];
    __hip_bfloat16 h = __float2bfloat16(v);
    WcH[(size_t)jp * 2048 + c] = h;
    WcL[(size_t)jp * 2048 + c] = __float2bfloat16(v - __bfloat162float(h));
  }
  for (int c = threadIdx.x; c < 512; c += 256)
    We[(size_t)jp * 512 + c] = __float2bfloat16(Wih[(size_t)src * 2560 + c]);
  for (int c = threadIdx.x; c < 1024; c += 256) {
    float v = Whh[(size_t)src * 1024 + c];
    __hip_bfloat16 h = __float2bfloat16(v);
    WhH[(size_t)jp * 1024 + c] = h;
    WhL[(size_t)jp * 1024 + c] = __float2bfloat16(v - __bfloat162float(h));
  }
  if (threadIdx.x == 0) { bihp[jp] = bih[src]; bhhp[jp] = bhh[src]; }
}

__global__ __launch_bounds__(256) void emb_gather(
    const int* __restrict__ tgt, const float* __restrict__ table,
    __hip_bfloat16* __restrict__ outb)
{
  const int row = blockIdx.x;          // b*64+t, 0..4095
  const int v = tgt[row];
  for (int c = threadIdx.x; c < 512; c += 256)
    outb[(size_t)row * 512 + c] = __float2bfloat16(table[(size_t)v * 512 + c]);
}

__global__ __launch_bounds__(256) void h0_init(
    const float* __restrict__ h0, float* __restrict__ hf,
    unsigned int* __restrict__ bar)
{
  const int i = blockIdx.x * 256 + threadIdx.x;   // grid 256 -> 65536
  hf[i] = h0[i];
  if (blockIdx.x == 0 && threadIdx.x < 256) bar[threadIdx.x] = 0u;
}

// ---------------- bf16 GEMM  C[M,N] = A[M,K] @ B[N,K]^T (single pass) -------
// 128x128 tile, 4 waves, BK=32, global_load_lds staging. Used for gxe (bf16 out).

__global__ __launch_bounds__(256) void gemm_bt(
    const short* __restrict__ A, const short* __restrict__ B,
    float* __restrict__ Cf, __hip_bfloat16* __restrict__ Cb,
    const float* __restrict__ bias, int M, int N, int K, int flags)
{
  __shared__ __align__(16) short As[128 * 32];
  __shared__ __align__(16) short Bs[128 * 32];
  const int tid = threadIdx.x, lane = tid & 63, w = tid >> 6;
  const int m0 = blockIdx.y * 128, n0 = blockIdx.x * 128;
  const int wm = (w >> 1) * 64, wn = (w & 1) * 64;
  const int srow = lane >> 2, scol = (lane & 3) * 8;
  f32x4 zero = {0.f, 0.f, 0.f, 0.f};
  f32x4 acc[4][4];
#pragma unroll
  for (int i = 0; i < 4; ++i)
#pragma unroll
    for (int j = 0; j < 4; ++j) acc[i][j] = zero;

  for (int k0 = 0; k0 < K; k0 += 32) {
    __syncthreads();
#pragma unroll
    for (int s = 0; s < 2; ++s) {
      const int chunk = w * 2 + s;
      const int r = chunk * 16 + srow;
      gld16(A + (size_t)(m0 + r) * K + k0 + scol, As + chunk * 512);
      gld16(B + (size_t)(n0 + r) * K + k0 + scol, Bs + chunk * 512);
    }
    __syncthreads();
    const int fm = lane & 15, fq = lane >> 4;
    short8 af[4], bq[4];
#pragma unroll
    for (int i = 0; i < 4; ++i)
      af[i] = *(const short8*)(As + (wm + i * 16 + fm) * 32 + fq * 8);
#pragma unroll
    for (int j = 0; j < 4; ++j)
      bq[j] = *(const short8*)(Bs + (wn + j * 16 + fm) * 32 + fq * 8);
#pragma unroll
    for (int i = 0; i < 4; ++i)
#pragma unroll
      for (int j = 0; j < 4; ++j)
        acc[i][j] = __builtin_amdgcn_mfma_f32_16x16x32_bf16(af[i], bq[j], acc[i][j], 0, 0, 0);
  }

  const int cn = lane & 15, cq = (lane >> 4) * 4;
#pragma unroll
  for (int i = 0; i < 4; ++i)
#pragma unroll
    for (int j = 0; j < 4; ++j)
#pragma unroll
      for (int r = 0; r < 4; ++r) {
        const int m = m0 + wm + i * 16 + cq + r;
        const int n = n0 + wn + j * 16 + cn;
        float v = acc[i][j][r];
        if (flags & FLAG_ACC) v += Cf[(size_t)m * N + n];
        if (bias) v += bias[n];
        if (flags & FLAG_BF) Cb[(size_t)m * N + n] = __float2bfloat16(v);
        else                 Cf[(size_t)m * N + n] = v;
      }
}

// ---------------- fused split-bf16 triple GEMM --------------------------------
// C = AH@BH^T + AL@BH^T + AH@BL^T  (effective-fp32 product), one staging pass.

__global__ __launch_bounds__(256) void gemm_bt3(
    const short* __restrict__ AH, const short* __restrict__ AL,
    const short* __restrict__ BH, const short* __restrict__ BL,
    float* __restrict__ Cf, int M, int N, int K)
{
  __shared__ __align__(16) short AsH[128 * 32];
  __shared__ __align__(16) short AsL[128 * 32];
  __shared__ __align__(16) short BsH[128 * 32];
  __shared__ __align__(16) short BsL[128 * 32];
  const int tid = threadIdx.x, lane = tid & 63, w = tid >> 6;
  const int m0 = blockIdx.y * 128, n0 = blockIdx.x * 128;
  const int wm = (w >> 1) * 64, wn = (w & 1) * 64;
  const int srow = lane >> 2, scol = (lane & 3) * 8;
  f32x4 zero = {0.f, 0.f, 0.f, 0.f};
  f32x4 acc[4][4];
#pragma unroll
  for (int i = 0; i < 4; ++i)
#pragma unroll
    for (int j = 0; j < 4; ++j) acc[i][j] = zero;

  for (int k0 = 0; k0 < K; k0 += 32) {
    __syncthreads();
#pragma unroll
    for (int s = 0; s < 2; ++s) {
      const int chunk = w * 2 + s;
      const int r = chunk * 16 + srow;
      const size_t ao = (size_t)(m0 + r) * K + k0 + scol;
      const size_t bo = (size_t)(n0 + r) * K + k0 + scol;
      gld16(AH + ao, AsH + chunk * 512);
      gld16(AL + ao, AsL + chunk * 512);
      gld16(BH + bo, BsH + chunk * 512);
      gld16(BL + bo, BsL + chunk * 512);
    }
    __syncthreads();
    const int fm = lane & 15, fq = lane >> 4;
    short8 ah[4], al[4], bh[4], bl[4];
#pragma unroll
    for (int i = 0; i < 4; ++i) {
      const int off = (wm + i * 16 + fm) * 32 + fq * 8;
      ah[i] = *(const short8*)(AsH + off);
      al[i] = *(const short8*)(AsL + off);
    }
#pragma unroll
    for (int j = 0; j < 4; ++j) {
      const int off = (wn + j * 16 + fm) * 32 + fq * 8;
      bh[j] = *(const short8*)(BsH + off);
      bl[j] = *(const short8*)(BsL + off);
    }
#pragma unroll
    for (int i = 0; i < 4; ++i)
#pragma unroll
      for (int j = 0; j < 4; ++j) {
        acc[i][j] = __builtin_amdgcn_mfma_f32_16x16x32_bf16(ah[i], bh[j], acc[i][j], 0, 0, 0);
        acc[i][j] = __builtin_amdgcn_mfma_f32_16x16x32_bf16(al[i], bh[j], acc[i][j], 0, 0, 0);
        acc[i][j] = __builtin_amdgcn_mfma_f32_16x16x32_bf16(ah[i], bl[j], acc[i][j], 0, 0, 0);
      }
  }

  const int cn = lane & 15, cq = (lane >> 4) * 4;
#pragma unroll
  for (int i = 0; i < 4; ++i)
#pragma unroll
    for (int j = 0; j < 4; ++j)
#pragma unroll
      for (int r = 0; r < 4; ++r) {
        const int m = m0 + wm + i * 16 + cq + r;
        const int n = n0 + wn + j * 16 + cn;
        Cf[(size_t)m * N + n] = acc[i][j][r];
      }
}

// ---------------- persistent recurrence (cooperative, custom barrier) --------

__global__ __launch_bounds__(512, 1) void recurrence_kernel(
    const float* __restrict__ ctxW, const int* __restrict__ lens,
    const short* __restrict__ WhH, const short* __restrict__ WhL,
    const float* __restrict__ ctxWc, const __hip_bfloat16* __restrict__ gxe,
    const float* __restrict__ bhhp, float* __restrict__ hf,
    float* __restrict__ attn, float* __restrict__ ghG,
    unsigned int* __restrict__ bar, float* __restrict__ out)
{
  const int blk = blockIdx.x;
  const int tid = threadIdx.x;

  // phase1/attn
  __shared__ float hs[1024];
  __shared__ float part[256];
  // phase1/gh: h slice re-split to bf16 (16 batches x 1024, +8 pad vs banks)
  __shared__ __align__(16) short AsH[16 * 1032];
  __shared__ __align__(16) short AsL[16 * 1032];
  __shared__ f32x4 psk[4][64];
  // phase2/gate
  __shared__ float ghs[48 * 17];
  __shared__ float wv[16][64];
  __shared__ short lidx[16][64];
  __shared__ int   cnt[16];
  __shared__ float ps0[256], ps1[256], ps2[256];

  // gh block geometry (XCD-aware: blk%8 == XCD heuristic; 4 bc-siblings of a
  // j-chunk land on one XCD -> Whh footprint 1.5MB/XCD, L2-resident)
  const int g = blk - 64;              // 0..191 for gh blocks
  const int xcd = g & 7, s = g >> 3;   // s: 0..23
  const int jc2 = xcd * 6 + (s >> 2);  // 0..47 -> 64 j-rows each
  const int bc2 = s & 3;               // 16 batches each

  for (int t = 0; t < 64; ++t) {
    // ================= phase 1 =================
    if (blk < 64) {
      // ---- attn scores + masked softmax for batch b (r4-verified math) ----
      const int b = blk;
      const int len = lens[b];
      for (int i = tid; i < 1024; i += 512)
        hs[i] = AL(hf + b * 1024 + i);
      __syncthreads();
      if (tid < 256) {
        const int l = tid >> 2, q = tid & 3;
        float sx = 0.f, sy = 0.f, sz = 0.f, sw = 0.f;
        if (l < len) {
          const float4* row = (const float4*)(ctxW + ((size_t)(b * 64 + l)) * 1024 + q * 256);
          const float4* hh = (const float4*)(hs + q * 256);
#pragma unroll 8
          for (int i = 0; i < 64; ++i) {
            float4 a = row[i], c = hh[i];
            sx += a.x * c.x; sy += a.y * c.y; sz += a.z * c.z; sw += a.w * c.w;
          }
        }
        part[tid] = (sx + sy) + (sz + sw);
      }
      __syncthreads();
      if (tid < 64) {   // wave 0; tid == context position
        float sc = part[tid * 4] + part[tid * 4 + 1] + part[tid * 4 + 2] + part[tid * 4 + 3];
        if (tid >= len) sc = -1e9f;
        float m = sc;
#pragma unroll
        for (int off = 32; off > 0; off >>= 1) m = fmaxf(m, __shfl_xor(m, off));
        float e = __expf(sc - m);
        float sum = e;
#pragma unroll
        for (int off = 32; off > 0; off >>= 1) sum += __shfl_xor(sum, off);
        AS(attn + b * 64 + tid, e / sum);
      }
    } else {
      // ---- gh = Whh[64 j-rows] @ h[16 batches], split-bf16 3-pass MFMA ----
      // stage h slice: fp32 flagged loads -> bf16 hi/lo in LDS
      for (int i = tid; i < 16384; i += 512) {
        const int row = i >> 10, col = i & 1023;
        float v = AL(hf + (bc2 * 16 + row) * 1024 + col);
        __hip_bfloat16 hh = __float2bfloat16(v);
        AsH[row * 1032 + col] = *reinterpret_cast<short*>(&hh);
        __hip_bfloat16 hl = __float2bfloat16(v - __bfloat162float(hh));
        AsL[row * 1032 + col] = *reinterpret_cast<short*>(&hl);
      }
      __syncthreads();
      const int lane = tid & 63, w = tid >> 6;
      const int fm = lane & 15, fq = lane >> 4;
      const int jsub = w & 3, khalf = w >> 2;   // 8 waves: 4 j-subtiles x 2 K-halves
      const int jr = jc2 * 64 + jsub * 16 + fm;
      const short* bh = WhH + (size_t)jr * 1024 + fq * 8;
      const short* bl = WhL + (size_t)jr * 1024 + fq * 8;
      const short* arH = AsH + fm * 1032 + fq * 8;
      const short* arL = AsL + fm * 1032 + fq * 8;
      f32x4 acc = {0.f, 0.f, 0.f, 0.f};
      const int kbeg = khalf * 512;
#pragma unroll 4
      for (int k = kbeg; k < kbeg + 512; k += 32) {
        short8 aH = *(const short8*)(arH + k);
        short8 aL = *(const short8*)(arL + k);
        short8 b0 = *(const short8*)(bh + k);
        short8 c0 = *(const short8*)(bl + k);
        acc = __builtin_amdgcn_mfma_f32_16x16x32_bf16(aH, b0, acc, 0, 0, 0);
        acc = __builtin_amdgcn_mfma_f32_16x16x32_bf16(aL, b0, acc, 0, 0, 0);
        acc = __builtin_amdgcn_mfma_f32_16x16x32_bf16(aH, c0, acc, 0, 0, 0);
      }
      if (khalf) psk[jsub][lane] = acc;
      __syncthreads();
      if (!khalf) {
        f32x4 o = psk[jsub][lane];
        acc.x += o.x; acc.y += o.y; acc.z += o.z; acc.w += o.w;
        // C layout (verified): j-row = fm, batch = fq*4 + r
        const size_t bidx = (size_t)jr * 64 + bc2 * 16 + fq * 4;
        AS(ghG + bidx + 0, acc.x);
        AS(ghG + bidx + 1, acc.y);
        AS(ghG + bidx + 2, acc.z);
        AS(ghG + bidx + 3, acc.w);
      }
    }

    // ---- barrier A (no acquire -> no L2 invalidate) ----
    __syncthreads();
    if (tid == 0) {
      __hip_atomic_fetch_add(&bar[t * 2], 1u, __ATOMIC_RELAXED, __HIP_MEMORY_SCOPE_AGENT);
      while (AL(&bar[t * 2]) < 256u) __builtin_amdgcn_s_sleep(2);
    }
    __syncthreads();

    // ================= phase 2: gate (r7-verified, flagged I/O) =================
    {
      const int jc = blk & 63, bc = blk >> 6;
      const int j0 = jc * 48, b0 = bc * 16;
      if (tid < 16) cnt[tid] = 0;
      for (int i = tid; i < 768; i += 512) {
        const int row = i >> 4, col = i & 15;
        ghs[row * 17 + col] = AL(ghG + (size_t)(j0 + row) * 64 + b0 + col);
      }
      __syncthreads();
      if (tid < 256) {
        const int bb = tid >> 4, l4 = (tid & 15) * 4;
        const int b = b0 + bb, len = lens[b];
#pragma unroll
        for (int k = 0; k < 4; ++k) {
          const int l = l4 + k;
          const float wl = AL(attn + b * 64 + l);
          if (l < len && wl >= 1e-8f) {
            const int pos = atomicAdd(&cnt[bb], 1);
            lidx[bb][pos] = (short)l;
            wv[bb][pos] = wl;
          }
        }
      }
      __syncthreads();

      const int tl = tid & 255;
      const int bb = tl >> 4, jg = tl & 15;
      const int b = b0 + bb;
      const int n = cnt[bb];
      const int nh = n >> 1;
      const int ibeg = (tid < 256) ? 0 : nh;
      const int iend = (tid < 256) ? nh : n;
      float g0 = 0.f, g1 = 0.f, g2 = 0.f;
      const float* base = ctxWc + (size_t)(b * 64) * 3072 + j0 + jg * 3;
      int i = ibeg;
      for (; i + 3 < iend; i += 4) {          // 4 outstanding scattered loads
        const float w0 = wv[bb][i],     w1 = wv[bb][i + 1];
        const float w2 = wv[bb][i + 2], w3 = wv[bb][i + 3];
        const float* p0 = base + (size_t)lidx[bb][i] * 3072;
        const float* p1 = base + (size_t)lidx[bb][i + 1] * 3072;
        const float* p2 = base + (size_t)lidx[bb][i + 2] * 3072;
        const float* p3 = base + (size_t)lidx[bb][i + 3] * 3072;
        const float a0 = __builtin_nontemporal_load(p0);
        const float a1 = __builtin_nontemporal_load(p0 + 1);
        const float a2 = __builtin_nontemporal_load(p0 + 2);
        const float b0v = __builtin_nontemporal_load(p1);
        const float b1v = __builtin_nontemporal_load(p1 + 1);
        const float b2v = __builtin_nontemporal_load(p1 + 2);
        const float c0 = __builtin_nontemporal_load(p2);
        const float c1 = __builtin_nontemporal_load(p2 + 1);
        const float c2 = __builtin_nontemporal_load(p2 + 2);
        const float d0 = __builtin_nontemporal_load(p3);
        const float d1 = __builtin_nontemporal_load(p3 + 1);
        const float d2 = __builtin_nontemporal_load(p3 + 2);
        g0 += (w0 * a0 + w1 * b0v) + (w2 * c0 + w3 * d0);
        g1 += (w0 * a1 + w1 * b1v) + (w2 * c1 + w3 * d1);
        g2 += (w0 * a2 + w1 * b2v) + (w2 * c2 + w3 * d2);
      }
      for (; i < iend; ++i) {
        const float wa = wv[bb][i];
        const float* pa = base + (size_t)lidx[bb][i] * 3072;
        g0 += wa * __builtin_nontemporal_load(pa);
        g1 += wa * __builtin_nontemporal_load(pa + 1);
        g2 += wa * __builtin_nontemporal_load(pa + 2);
      }
      if (tid >= 256) { ps0[tl] = g0; ps1[tl] = g1; ps2[tl] = g2; }
      __syncthreads();
      if (tid < 256) {
        g0 += ps0[tl]; g1 += ps1[tl]; g2 += ps2[tl];

        const int jp = j0 + jg * 3;
        const __hip_bfloat16* ge = gxe + (size_t)(b * 64 + t) * 3072 + jp;
        const float gxr = g0 + __bfloat162float(ge[0]);
        const float gxz = g1 + __bfloat162float(ge[1]);
        const float gxn = g2 + __bfloat162float(ge[2]);
        const float ghr = ghs[(jg * 3 + 0) * 17 + bb] + bhhp[jp + 0];
        const float ghz = ghs[(jg * 3 + 1) * 17 + bb] + bhhp[jp + 1];
        const float ghn = ghs[(jg * 3 + 2) * 17 + bb] + bhhp[jp + 2];
        const float rr = 1.f / (1.f + __expf(-(gxr + ghr)));
        const float zz = 1.f / (1.f + __expf(-(gxz + ghz)));
        const float nn = tanhf(gxn + rr * ghn);
        const int u = jc * 16 + jg;
        const float hold = AL(hf + b * 1024 + u);
        const float hn = (1.f - zz) * nn + zz * hold;
        out[(size_t)(b * 64 + t) * 1024 + u] = hn;
        AS(hf + b * 1024 + u, hn);
        if (t == 63) out[(size_t)64 * 64 * 1024 + b * 1024 + u] = hn;
      }
    }

    // ---- barrier B ----
    if (t != 63) {
      __syncthreads();
      if (tid == 0) {
        __hip_atomic_fetch_add(&bar[t * 2 + 1], 1u, __ATOMIC_RELAXED, __HIP_MEMORY_SCOPE_AGENT);
        while (AL(&bar[t * 2 + 1]) < 256u) __builtin_amdgcn_s_sleep(2);
      }
      __syncthreads();
    }
  }
}

// ---------------- launcher ----------------

extern "C" void kernel_launch(void* const* d_in, const int* in_sizes, int n_in,
                              void* d_out, int out_size, void* d_ws, size_t ws_size,
                              hipStream_t stream)
{
  const int*   tgt  = (const int*)  d_in[0];
  const float* ctx  = (const float*)d_in[1];
  const float* h0   = (const float*)d_in[2];
  const int*   lens = (const int*)  d_in[3];
  const float* embt = (const float*)d_in[4];
  const float* Wa   = (const float*)d_in[5];
  const float* Wih  = (const float*)d_in[6];
  const float* Whh  = (const float*)d_in[7];
  const float* bih  = (const float*)d_in[8];
  const float* bhh  = (const float*)d_in[9];
  float* out = (float*)d_out;

  char* p = (char*)d_ws;
  auto take = [&](size_t bytes) {
    char* q = p;
    p += (bytes + 255) & ~(size_t)255;
    return q;
  };
  short* ctx_hi = (short*)take((size_t)8388608 * 2);
  short* ctx_lo = (short*)take((size_t)8388608 * 2);
  short* Wa_hi  = (short*)take((size_t)2097152 * 2);
  short* Wa_lo  = (short*)take((size_t)2097152 * 2);
  short* WcH    = (short*)take((size_t)3072 * 2048 * 2);
  short* WcL    = (short*)take((size_t)3072 * 2048 * 2);
  short* We_p   = (short*)take((size_t)3072 * 512 * 2);
  short* WhH    = (short*)take((size_t)3072 * 1024 * 2);
  short* WhL    = (short*)take((size_t)3072 * 1024 * 2);
  float* bih_p  = (float*)take(3072 * 4);
  float* bhh_p  = (float*)take(3072 * 4);
  short* emb_bf = (short*)take((size_t)4096 * 512 * 2);
  float* ctxW   = (float*)take((size_t)4096 * 1024 * 4);
  float* ctxWc  = (float*)take((size_t)4096 * 3072 * 4);
  short* gxe    = (short*)take((size_t)4096 * 3072 * 2);
  float* hf     = (float*)take((size_t)65536 * 4);
  float* attn   = (float*)take((size_t)4096 * 4);
  float* ghG    = (float*)take((size_t)3072 * 64 * 4);
  unsigned int* bar = (unsigned int*)take(256 * 4);

  // prologue: conversions
  split_bf16_kernel<<<2048, 256, 0, stream>>>(ctx, (__hip_bfloat16*)ctx_hi,
                                              (__hip_bfloat16*)ctx_lo, 8388608);
  split_bf16_kernel<<<1024, 256, 0, stream>>>(Wa, (__hip_bfloat16*)Wa_hi,
                                              (__hip_bfloat16*)Wa_lo, 2097152);
  prep_weights<<<3072, 256, 0, stream>>>(Wih, Whh, bih, bhh,
      (__hip_bfloat16*)WcH, (__hip_bfloat16*)WcL, (__hip_bfloat16*)We_p,
      (__hip_bfloat16*)WhH, (__hip_bfloat16*)WhL, bih_p, bhh_p);
  emb_gather<<<4096, 256, 0, stream>>>(tgt, embt, (__hip_bfloat16*)emb_bf);
  h0_init<<<256, 256, 0, stream>>>(h0, hf, bar);

  // ctxW = ctx @ Wa^T   (split-bf16 fused 3-product, fp32 out)
  gemm_bt3<<<dim3(8, 32), 256, 0, stream>>>(ctx_hi, ctx_lo, Wa_hi, Wa_lo,
                                            ctxW, 4096, 1024, 2048);
  // ctxWc = ctx @ Wc_perm^T (split-bf16 fused 3-product, fp32 out)
  gemm_bt3<<<dim3(24, 32), 256, 0, stream>>>(ctx_hi, ctx_lo, WcH, WcL,
                                             ctxWc, 4096, 3072, 2048);
  // gxe = emb @ We_perm^T + b_ih (bf16 out; |gxe| ~ 3e-3, rounding negligible)
  gemm_bt<<<dim3(24, 32), 256, 0, stream>>>(emb_bf, We_p, nullptr,
                                            (__hip_bfloat16*)gxe, bih_p,
                                            4096, 3072, 512, FLAG_BF);

  // persistent recurrence: one cooperative dispatch, custom flag barriers
  {
    const float* ctxWb = ctxW; const float* ctxWcB = ctxWc;
    const short* WhHc = WhH;  const short* WhLc = WhL;
    const __hip_bfloat16* gxeB = (const __hip_bfloat16*)gxe;
    const float* bhhB = bhh_p;
    void* kargs[] = {
      (void*)&ctxWb, (void*)&lens, (void*)&WhHc, (void*)&WhLc,
      (void*)&ctxWcB, (void*)&gxeB, (void*)&bhhB,
      (void*)&hf, (void*)&attn, (void*)&ghG, (void*)&bar, (void*)&out
    };
    hipLaunchCooperativeKernel((void*)recurrence_kernel, dim3(256), dim3(512),
                               kargs, 0, stream);
  }
}

// Round 7
// 2831.504 us; speedup vs baseline: 1.2360x; 1.2360x over previous
//
#include <hip/hip_runtime.h>
#include <hip/hip_bf16.h>

// DecoderRNNsearch on MI355X — round 9 (resubmit; r6 bench never acquired a GPU).
//   Persistent v2: invalidation-free barrier (proven r8: FETCH 1.76->1.06 GB)
//   + vectorized coherent data movement:
//     - h stored PACKED (hi_bf16<<16|lo_bf16) by gate (1 AS/thread);
//       gh stages via batched global_load_dwordx4 sc0 sc1 (coherent,
//       4-deep, one waitcnt/batch) + unpack to LDS.
//     - ghG / attn / hs staging all vectorized coherent (dwordx4 sc0 sc1).
//     - explicit s_waitcnt vmcnt(0) before each barrier arrive (asm stores
//       are outside the compiler's waitcnt model).
//     - attn dot over all 512 threads; s_sleep(1).
//   Numerics identical to the passing r7/r8 path (fp32 / split-bf16 only).

using short8  = __attribute__((ext_vector_type(8))) short;
using short4t = __attribute__((ext_vector_type(4))) short;
using f32x4   = __attribute__((ext_vector_type(4))) float;
using u32x4   = __attribute__((ext_vector_type(4))) unsigned int;

#define FLAG_ACC 1
#define FLAG_BF  2

#define AL(p)    __hip_atomic_load((p), __ATOMIC_RELAXED, __HIP_MEMORY_SCOPE_AGENT)
#define AS(p, v) __hip_atomic_store((p), (v), __ATOMIC_RELAXED, __HIP_MEMORY_SCOPE_AGENT)

__device__ __forceinline__ void gld16(const void* g, void* l) {
  __builtin_amdgcn_global_load_lds(
      (const __attribute__((address_space(1))) unsigned int*)g,
      (__attribute__((address_space(3))) unsigned int*)l, 16, 0, 0);
}

// coherent (LLC) vector load/store helpers — sc0 sc1 = device scope
__device__ __forceinline__ f32x4 ldc_f4(const float* p) {
  f32x4 r;
  asm volatile("global_load_dwordx4 %0, %1, off sc0 sc1\n\ts_waitcnt vmcnt(0)"
               : "=v"(r) : "v"(p) : "memory");
  return r;
}
__device__ __forceinline__ void ldc_u4x4(
    const unsigned int* p0, const unsigned int* p1,
    const unsigned int* p2, const unsigned int* p3,
    u32x4& r0, u32x4& r1, u32x4& r2, u32x4& r3) {
  asm volatile(
      "global_load_dwordx4 %0, %4, off sc0 sc1\n\t"
      "global_load_dwordx4 %1, %5, off sc0 sc1\n\t"
      "global_load_dwordx4 %2, %6, off sc0 sc1\n\t"
      "global_load_dwordx4 %3, %7, off sc0 sc1\n\t"
      "s_waitcnt vmcnt(0)"
      : "=&v"(r0), "=&v"(r1), "=&v"(r2), "=&v"(r3)
      : "v"(p0), "v"(p1), "v"(p2), "v"(p3)
      : "memory");
}
__device__ __forceinline__ void stc_f4(float* p, f32x4 v) {
  asm volatile("global_store_dwordx4 %0, %1, off sc0 sc1"
               :: "v"(p), "v"(v) : "memory");
}
__device__ __forceinline__ void wait_vm0() {
  asm volatile("s_waitcnt vmcnt(0)" ::: "memory");
}

// ---------------- conversion / prep kernels ----------------

__global__ __launch_bounds__(256) void split_bf16_kernel(
    const float* __restrict__ x, __hip_bfloat16* __restrict__ hi,
    __hip_bfloat16* __restrict__ lo, int n)
{
  int i = blockIdx.x * blockDim.x + threadIdx.x;
  int stride = gridDim.x * blockDim.x;
  for (; i < n; i += stride) {
    float v = x[i];
    __hip_bfloat16 h = __float2bfloat16(v);
    hi[i] = h;
    lo[i] = __float2bfloat16(v - __bfloat162float(h));
  }
}

// permute rows j' = 3u+g  <-  source row g*1024+u ; split to bf16 hi/lo
__global__ __launch_bounds__(256) void prep_weights(
    const float* __restrict__ Wih, const float* __restrict__ Whh,
    const float* __restrict__ bih, const float* __restrict__ bhh,
    __hip_bfloat16* __restrict__ WcH, __hip_bfloat16* __restrict__ WcL,
    __hip_bfloat16* __restrict__ We,
    __hip_bfloat16* __restrict__ WhH, __hip_bfloat16* __restrict__ WhL,
    float* __restrict__ bihp, float* __restrict__ bhhp)
{
  const int jp = blockIdx.x;           // 0..3071
  const int u = jp / 3, g = jp - 3 * u;
  const int src = g * 1024 + u;
  for (int c = threadIdx.x; c < 2048; c += 256) {
    float v = Wih[(size_t)src * 2560 + 512 + c];
    __hip_bfloat16 h = __float2bfloat16(v);
    WcH[(size_t)jp * 2048 + c] = h;
    WcL[(size_t)jp * 2048 + c] = __float2bfloat16(v - __bfloat162float(h));
  }
  for (int c = threadIdx.x; c < 512; c += 256)
    We[(size_t)jp * 512 + c] = __float2bfloat16(Wih[(size_t)src * 2560 + c]);
  for (int c = threadIdx.x; c < 1024; c += 256) {
    float v = Whh[(size_t)src * 1024 + c];
    __hip_bfloat16 h = __float2bfloat16(v);
    WhH[(size_t)jp * 1024 + c] = h;
    WhL[(size_t)jp * 1024 + c] = __float2bfloat16(v - __bfloat162float(h));
  }
  if (threadIdx.x == 0) { bihp[jp] = bih[src]; bhhp[jp] = bhh[src]; }
}

__global__ __launch_bounds__(256) void emb_gather(
    const int* __restrict__ tgt, const float* __restrict__ table,
    __hip_bfloat16* __restrict__ outb)
{
  const int row = blockIdx.x;          // b*64+t, 0..4095
  const int v = tgt[row];
  for (int c = threadIdx.x; c < 512; c += 256)
    outb[(size_t)row * 512 + c] = __float2bfloat16(table[(size_t)v * 512 + c]);
}

__global__ __launch_bounds__(256) void h0_init(
    const float* __restrict__ h0, float* __restrict__ hf,
    unsigned int* __restrict__ hsp, unsigned int* __restrict__ bar)
{
  const int i = blockIdx.x * 256 + threadIdx.x;   // grid 256 -> 65536
  float v = h0[i];
  hf[i] = v;
  __hip_bfloat16 hh = __float2bfloat16(v);
  unsigned short uh = *reinterpret_cast<unsigned short*>(&hh);
  __hip_bfloat16 hl = __float2bfloat16(v - __bfloat162float(hh));
  unsigned short ul = *reinterpret_cast<unsigned short*>(&hl);
  hsp[i] = ((unsigned int)uh << 16) | ul;
  if (blockIdx.x == 0 && threadIdx.x < 256) bar[threadIdx.x] = 0u;
}

// ---------------- bf16 GEMM  C[M,N] = A[M,K] @ B[N,K]^T (single pass) -------

__global__ __launch_bounds__(256) void gemm_bt(
    const short* __restrict__ A, const short* __restrict__ B,
    float* __restrict__ Cf, __hip_bfloat16* __restrict__ Cb,
    const float* __restrict__ bias, int M, int N, int K, int flags)
{
  __shared__ __align__(16) short As[128 * 32];
  __shared__ __align__(16) short Bs[128 * 32];
  const int tid = threadIdx.x, lane = tid & 63, w = tid >> 6;
  const int m0 = blockIdx.y * 128, n0 = blockIdx.x * 128;
  const int wm = (w >> 1) * 64, wn = (w & 1) * 64;
  const int srow = lane >> 2, scol = (lane & 3) * 8;
  f32x4 zero = {0.f, 0.f, 0.f, 0.f};
  f32x4 acc[4][4];
#pragma unroll
  for (int i = 0; i < 4; ++i)
#pragma unroll
    for (int j = 0; j < 4; ++j) acc[i][j] = zero;

  for (int k0 = 0; k0 < K; k0 += 32) {
    __syncthreads();
#pragma unroll
    for (int s = 0; s < 2; ++s) {
      const int chunk = w * 2 + s;
      const int r = chunk * 16 + srow;
      gld16(A + (size_t)(m0 + r) * K + k0 + scol, As + chunk * 512);
      gld16(B + (size_t)(n0 + r) * K + k0 + scol, Bs + chunk * 512);
    }
    __syncthreads();
    const int fm = lane & 15, fq = lane >> 4;
    short8 af[4], bq[4];
#pragma unroll
    for (int i = 0; i < 4; ++i)
      af[i] = *(const short8*)(As + (wm + i * 16 + fm) * 32 + fq * 8);
#pragma unroll
    for (int j = 0; j < 4; ++j)
      bq[j] = *(const short8*)(Bs + (wn + j * 16 + fm) * 32 + fq * 8);
#pragma unroll
    for (int i = 0; i < 4; ++i)
#pragma unroll
      for (int j = 0; j < 4; ++j)
        acc[i][j] = __builtin_amdgcn_mfma_f32_16x16x32_bf16(af[i], bq[j], acc[i][j], 0, 0, 0);
  }

  const int cn = lane & 15, cq = (lane >> 4) * 4;
#pragma unroll
  for (int i = 0; i < 4; ++i)
#pragma unroll
    for (int j = 0; j < 4; ++j)
#pragma unroll
      for (int r = 0; r < 4; ++r) {
        const int m = m0 + wm + i * 16 + cq + r;
        const int n = n0 + wn + j * 16 + cn;
        float v = acc[i][j][r];
        if (flags & FLAG_ACC) v += Cf[(size_t)m * N + n];
        if (bias) v += bias[n];
        if (flags & FLAG_BF) Cb[(size_t)m * N + n] = __float2bfloat16(v);
        else                 Cf[(size_t)m * N + n] = v;
      }
}

// ---------------- fused split-bf16 triple GEMM --------------------------------

__global__ __launch_bounds__(256) void gemm_bt3(
    const short* __restrict__ AH, const short* __restrict__ AL,
    const short* __restrict__ BH, const short* __restrict__ BL,
    float* __restrict__ Cf, int M, int N, int K)
{
  __shared__ __align__(16) short AsH[128 * 32];
  __shared__ __align__(16) short AsL[128 * 32];
  __shared__ __align__(16) short BsH[128 * 32];
  __shared__ __align__(16) short BsL[128 * 32];
  const int tid = threadIdx.x, lane = tid & 63, w = tid >> 6;
  const int m0 = blockIdx.y * 128, n0 = blockIdx.x * 128;
  const int wm = (w >> 1) * 64, wn = (w & 1) * 64;
  const int srow = lane >> 2, scol = (lane & 3) * 8;
  f32x4 zero = {0.f, 0.f, 0.f, 0.f};
  f32x4 acc[4][4];
#pragma unroll
  for (int i = 0; i < 4; ++i)
#pragma unroll
    for (int j = 0; j < 4; ++j) acc[i][j] = zero;

  for (int k0 = 0; k0 < K; k0 += 32) {
    __syncthreads();
#pragma unroll
    for (int s = 0; s < 2; ++s) {
      const int chunk = w * 2 + s;
      const int r = chunk * 16 + srow;
      const size_t ao = (size_t)(m0 + r) * K + k0 + scol;
      const size_t bo = (size_t)(n0 + r) * K + k0 + scol;
      gld16(AH + ao, AsH + chunk * 512);
      gld16(AL + ao, AsL + chunk * 512);
      gld16(BH + bo, BsH + chunk * 512);
      gld16(BL + bo, BsL + chunk * 512);
    }
    __syncthreads();
    const int fm = lane & 15, fq = lane >> 4;
    short8 ah[4], al[4], bh[4], bl[4];
#pragma unroll
    for (int i = 0; i < 4; ++i) {
      const int off = (wm + i * 16 + fm) * 32 + fq * 8;
      ah[i] = *(const short8*)(AsH + off);
      al[i] = *(const short8*)(AsL + off);
    }
#pragma unroll
    for (int j = 0; j < 4; ++j) {
      const int off = (wn + j * 16 + fm) * 32 + fq * 8;
      bh[j] = *(const short8*)(BsH + off);
      bl[j] = *(const short8*)(BsL + off);
    }
#pragma unroll
    for (int i = 0; i < 4; ++i)
#pragma unroll
      for (int j = 0; j < 4; ++j) {
        acc[i][j] = __builtin_amdgcn_mfma_f32_16x16x32_bf16(ah[i], bh[j], acc[i][j], 0, 0, 0);
        acc[i][j] = __builtin_amdgcn_mfma_f32_16x16x32_bf16(al[i], bh[j], acc[i][j], 0, 0, 0);
        acc[i][j] = __builtin_amdgcn_mfma_f32_16x16x32_bf16(ah[i], bl[j], acc[i][j], 0, 0, 0);
      }
  }

  const int cn = lane & 15, cq = (lane >> 4) * 4;
#pragma unroll
  for (int i = 0; i < 4; ++i)
#pragma unroll
    for (int j = 0; j < 4; ++j)
#pragma unroll
      for (int r = 0; r < 4; ++r) {
        const int m = m0 + wm + i * 16 + cq + r;
        const int n = n0 + wn + j * 16 + cn;
        Cf[(size_t)m * N + n] = acc[i][j][r];
      }
}

// ---------------- persistent recurrence (cooperative, custom barrier) --------

__global__ __launch_bounds__(512, 1) void recurrence_kernel(
    const float* __restrict__ ctxW, const int* __restrict__ lens,
    const short* __restrict__ WhH, const short* __restrict__ WhL,
    const float* __restrict__ ctxWc, const __hip_bfloat16* __restrict__ gxe,
    const float* __restrict__ bhhp, float* __restrict__ hf,
    unsigned int* __restrict__ hsp,
    float* __restrict__ attn, float* __restrict__ ghG,
    unsigned int* __restrict__ bar, float* __restrict__ out)
{
  const int blk = blockIdx.x;
  const int tid = threadIdx.x;

  // phase1/attn
  __shared__ float hs[1024];
  __shared__ float part[512];
  // phase1/gh: pre-split h slice (16 batches x 1024, stride 1032)
  __shared__ __align__(16) short AsH[16 * 1032];
  __shared__ __align__(16) short AsL[16 * 1032];
  __shared__ f32x4 psk[4][64];
  // phase2/gate
  __shared__ float ghs[48 * 17];
  __shared__ float wv[16][64];
  __shared__ short lidx[16][64];
  __shared__ int   cnt[16];
  __shared__ float ps0[256], ps1[256], ps2[256];

  // gh geometry: 192 blocks, 64 j-rows x 16 batches each, XCD-aware
  const int g = blk - 64;
  const int xcd = g & 7, s = g >> 3;
  const int jc2 = xcd * 6 + (s >> 2);  // 0..47, 64 j-rows each
  const int bc2 = s & 3;               // 16 batches

  for (int t = 0; t < 64; ++t) {
    // ================= phase 1 =================
    if (blk < 64) {
      // ---- attn scores + masked softmax for batch b ----
      const int b = blk;
      const int len = lens[b];
      if (tid < 256) {
        f32x4 v = ldc_f4(hf + b * 1024 + tid * 4);
        *(f32x4*)(hs + tid * 4) = v;
      }
      __syncthreads();
      {
        const int l = tid >> 3, q = tid & 7;   // 64 l x 8 d-chunks of 128
        float sx = 0.f, sy = 0.f, sz = 0.f, sw = 0.f;
        if (l < len) {
          const float4* row = (const float4*)(ctxW + ((size_t)(b * 64 + l)) * 1024 + q * 128);
          const float4* hh = (const float4*)(hs + q * 128);
#pragma unroll 8
          for (int i = 0; i < 32; ++i) {
            float4 a = row[i], c = hh[i];
            sx += a.x * c.x; sy += a.y * c.y; sz += a.z * c.z; sw += a.w * c.w;
          }
        }
        part[tid] = (sx + sy) + (sz + sw);
      }
      __syncthreads();
      if (tid < 64) {   // wave 0; tid == context position
        float sc = 0.f;
#pragma unroll
        for (int k = 0; k < 8; ++k) sc += part[tid * 8 + k];
        if (tid >= len) sc = -1e9f;
        float m = sc;
#pragma unroll
        for (int off = 32; off > 0; off >>= 1) m = fmaxf(m, __shfl_xor(m, off));
        float e = __expf(sc - m);
        float sum = e;
#pragma unroll
        for (int off = 32; off > 0; off >>= 1) sum += __shfl_xor(sum, off);
        AS(attn + b * 64 + tid, e / sum);
      }
    } else {
      // ---- stage pre-split h slice: 16K packed uints, coherent dwordx4 ----
      {
        const unsigned int* srcb = hsp + bc2 * 16 * 1024;
#pragma unroll
        for (int k = 0; k < 2; ++k) {
          const int c = tid + k * 2048;        // uint4-chunk id, 4096 total
          u32x4 r0, r1, r2, r3;
          ldc_u4x4(srcb + (size_t)(c) * 4,        srcb + (size_t)(c + 512) * 4,
                   srcb + (size_t)(c + 1024) * 4, srcb + (size_t)(c + 1536) * 4,
                   r0, r1, r2, r3);
#pragma unroll
          for (int j = 0; j < 4; ++j) {
            const int cc = c + j * 512;
            const u32x4 r = (j == 0) ? r0 : (j == 1) ? r1 : (j == 2) ? r2 : r3;
            const int row = cc >> 8, col = (cc & 255) * 4;
            short4t hi = { (short)(r.x >> 16), (short)(r.y >> 16),
                           (short)(r.z >> 16), (short)(r.w >> 16) };
            short4t lo = { (short)(r.x & 0xffff), (short)(r.y & 0xffff),
                           (short)(r.z & 0xffff), (short)(r.w & 0xffff) };
            *(short4t*)(AsH + row * 1032 + col) = hi;
            *(short4t*)(AsL + row * 1032 + col) = lo;
          }
        }
      }
      __syncthreads();
      // ---- gh = Whh[64 j-rows] @ h[16 batches], split-bf16 3-pass MFMA ----
      const int lane = tid & 63, w = tid >> 6;
      const int fm = lane & 15, fq = lane >> 4;
      const int jsub = w & 3, khalf = w >> 2;   // 8 waves: 4 j-subtiles x 2 K-halves
      const int jr = jc2 * 64 + jsub * 16 + fm;
      const short* bh = WhH + (size_t)jr * 1024 + fq * 8;
      const short* bl = WhL + (size_t)jr * 1024 + fq * 8;
      const short* arH = AsH + fm * 1032 + fq * 8;
      const short* arL = AsL + fm * 1032 + fq * 8;
      f32x4 acc = {0.f, 0.f, 0.f, 0.f};
      const int kbeg = khalf * 512;
#pragma unroll 4
      for (int k = kbeg; k < kbeg + 512; k += 32) {
        short8 aH = *(const short8*)(arH + k);
        short8 aL = *(const short8*)(arL + k);
        short8 b0 = *(const short8*)(bh + k);
        short8 c0 = *(const short8*)(bl + k);
        acc = __builtin_amdgcn_mfma_f32_16x16x32_bf16(aH, b0, acc, 0, 0, 0);
        acc = __builtin_amdgcn_mfma_f32_16x16x32_bf16(aL, b0, acc, 0, 0, 0);
        acc = __builtin_amdgcn_mfma_f32_16x16x32_bf16(aH, c0, acc, 0, 0, 0);
      }
      if (khalf) psk[jsub][lane] = acc;
      __syncthreads();
      if (!khalf) {
        f32x4 o = psk[jsub][lane];
        acc.x += o.x; acc.y += o.y; acc.z += o.z; acc.w += o.w;
        stc_f4(ghG + (size_t)jr * 64 + bc2 * 16 + fq * 4, acc);
      }
    }

    // ---- barrier A (no acquire -> no L2 invalidate) ----
    wait_vm0();
    __syncthreads();
    if (tid == 0) {
      __hip_atomic_fetch_add(&bar[t * 2], 1u, __ATOMIC_RELAXED, __HIP_MEMORY_SCOPE_AGENT);
      while (AL(&bar[t * 2]) < 256u) __builtin_amdgcn_s_sleep(1);
    }
    __syncthreads();

    // ================= phase 2: gate =================
    {
      const int jc = blk & 63, bc = blk >> 6;
      const int j0 = jc * 48, b0 = bc * 16;
      if (tid < 16) cnt[tid] = 0;
      if (tid < 192) {                          // ghs: 48x16 floats, coherent f4
        const int row = tid >> 2, col = (tid & 3) * 4;
        f32x4 v = ldc_f4(ghG + (size_t)(j0 + row) * 64 + b0 + col);
        ghs[row * 17 + col + 0] = v.x;
        ghs[row * 17 + col + 1] = v.y;
        ghs[row * 17 + col + 2] = v.z;
        ghs[row * 17 + col + 3] = v.w;
      }
      __syncthreads();
      if (tid < 256) {
        const int bb = tid >> 4, l4 = (tid & 15) * 4;
        const int b = b0 + bb, len = lens[b];
        f32x4 w4 = ldc_f4(attn + b * 64 + l4);
#pragma unroll
        for (int k = 0; k < 4; ++k) {
          const int l = l4 + k;
          const float wl = w4[k];
          if (l < len && wl >= 1e-8f) {
            const int pos = atomicAdd(&cnt[bb], 1);
            lidx[bb][pos] = (short)l;
            wv[bb][pos] = wl;
          }
        }
      }
      __syncthreads();

      const int tl = tid & 255;
      const int bb = tl >> 4, jg = tl & 15;
      const int b = b0 + bb;
      const int n = cnt[bb];
      const int nh = n >> 1;
      const int ibeg = (tid < 256) ? 0 : nh;
      const int iend = (tid < 256) ? nh : n;
      float g0 = 0.f, g1 = 0.f, g2 = 0.f;
      const float* base = ctxWc + (size_t)(b * 64) * 3072 + j0 + jg * 3;
      int i = ibeg;
      for (; i + 3 < iend; i += 4) {
        const float w0 = wv[bb][i],     w1 = wv[bb][i + 1];
        const float w2 = wv[bb][i + 2], w3 = wv[bb][i + 3];
        const float* p0 = base + (size_t)lidx[bb][i] * 3072;
        const float* p1 = base + (size_t)lidx[bb][i + 1] * 3072;
        const float* p2 = base + (size_t)lidx[bb][i + 2] * 3072;
        const float* p3 = base + (size_t)lidx[bb][i + 3] * 3072;
        const float a0 = __builtin_nontemporal_load(p0);
        const float a1 = __builtin_nontemporal_load(p0 + 1);
        const float a2 = __builtin_nontemporal_load(p0 + 2);
        const float b0v = __builtin_nontemporal_load(p1);
        const float b1v = __builtin_nontemporal_load(p1 + 1);
        const float b2v = __builtin_nontemporal_load(p1 + 2);
        const float c0 = __builtin_nontemporal_load(p2);
        const float c1 = __builtin_nontemporal_load(p2 + 1);
        const float c2 = __builtin_nontemporal_load(p2 + 2);
        const float d0 = __builtin_nontemporal_load(p3);
        const float d1 = __builtin_nontemporal_load(p3 + 1);
        const float d2 = __builtin_nontemporal_load(p3 + 2);
        g0 += (w0 * a0 + w1 * b0v) + (w2 * c0 + w3 * d0);
        g1 += (w0 * a1 + w1 * b1v) + (w2 * c1 + w3 * d1);
        g2 += (w0 * a2 + w1 * b2v) + (w2 * c2 + w3 * d2);
      }
      for (; i < iend; ++i) {
        const float wa = wv[bb][i];
        const float* pa = base + (size_t)lidx[bb][i] * 3072;
        g0 += wa * __builtin_nontemporal_load(pa);
        g1 += wa * __builtin_nontemporal_load(pa + 1);
        g2 += wa * __builtin_nontemporal_load(pa + 2);
      }
      if (tid >= 256) { ps0[tl] = g0; ps1[tl] = g1; ps2[tl] = g2; }
      __syncthreads();
      if (tid < 256) {
        g0 += ps0[tl]; g1 += ps1[tl]; g2 += ps2[tl];

        const int jp = j0 + jg * 3;
        const __hip_bfloat16* ge = gxe + (size_t)(b * 64 + t) * 3072 + jp;
        const float gxr = g0 + __bfloat162float(ge[0]);
        const float gxz = g1 + __bfloat162float(ge[1]);
        const float gxn = g2 + __bfloat162float(ge[2]);
        const float ghr = ghs[(jg * 3 + 0) * 17 + bb] + bhhp[jp + 0];
        const float ghz = ghs[(jg * 3 + 1) * 17 + bb] + bhhp[jp + 1];
        const float ghn = ghs[(jg * 3 + 2) * 17 + bb] + bhhp[jp + 2];
        const float rr = 1.f / (1.f + __expf(-(gxr + ghr)));
        const float zz = 1.f / (1.f + __expf(-(gxz + ghz)));
        const float nn = tanhf(gxn + rr * ghn);
        const int u = jc * 16 + jg;
        const float hold = AL(hf + b * 1024 + u);
        const float hn = (1.f - zz) * nn + zz * hold;
        out[(size_t)(b * 64 + t) * 1024 + u] = hn;
        AS(hf + b * 1024 + u, hn);
        __hip_bfloat16 hh = __float2bfloat16(hn);
        unsigned short uh = *reinterpret_cast<unsigned short*>(&hh);
        __hip_bfloat16 hl = __float2bfloat16(hn - __bfloat162float(hh));
        unsigned short ul = *reinterpret_cast<unsigned short*>(&hl);
        AS(hsp + b * 1024 + u, ((unsigned int)uh << 16) | ul);
        if (t == 63) out[(size_t)64 * 64 * 1024 + b * 1024 + u] = hn;
      }
    }

    // ---- barrier B ----
    if (t != 63) {
      wait_vm0();
      __syncthreads();
      if (tid == 0) {
        __hip_atomic_fetch_add(&bar[t * 2 + 1], 1u, __ATOMIC_RELAXED, __HIP_MEMORY_SCOPE_AGENT);
        while (AL(&bar[t * 2 + 1]) < 256u) __builtin_amdgcn_s_sleep(1);
      }
      __syncthreads();
    }
  }
}

// ---------------- launcher ----------------

extern "C" void kernel_launch(void* const* d_in, const int* in_sizes, int n_in,
                              void* d_out, int out_size, void* d_ws, size_t ws_size,
                              hipStream_t stream)
{
  const int*   tgt  = (const int*)  d_in[0];
  const float* ctx  = (const float*)d_in[1];
  const float* h0   = (const float*)d_in[2];
  const int*   lens = (const int*)  d_in[3];
  const float* embt = (const float*)d_in[4];
  const float* Wa   = (const float*)d_in[5];
  const float* Wih  = (const float*)d_in[6];
  const float* Whh  = (const float*)d_in[7];
  const float* bih  = (const float*)d_in[8];
  const float* bhh  = (const float*)d_in[9];
  float* out = (float*)d_out;

  char* p = (char*)d_ws;
  auto take = [&](size_t bytes) {
    char* q = p;
    p += (bytes + 255) & ~(size_t)255;
    return q;
  };
  short* ctx_hi = (short*)take((size_t)8388608 * 2);
  short* ctx_lo = (short*)take((size_t)8388608 * 2);
  short* Wa_hi  = (short*)take((size_t)2097152 * 2);
  short* Wa_lo  = (short*)take((size_t)2097152 * 2);
  short* WcH    = (short*)take((size_t)3072 * 2048 * 2);
  short* WcL    = (short*)take((size_t)3072 * 2048 * 2);
  short* We_p   = (short*)take((size_t)3072 * 512 * 2);
  short* WhH    = (short*)take((size_t)3072 * 1024 * 2);
  short* WhL    = (short*)take((size_t)3072 * 1024 * 2);
  float* bih_p  = (float*)take(3072 * 4);
  float* bhh_p  = (float*)take(3072 * 4);
  short* emb_bf = (short*)take((size_t)4096 * 512 * 2);
  float* ctxW   = (float*)take((size_t)4096 * 1024 * 4);
  float* ctxWc  = (float*)take((size_t)4096 * 3072 * 4);
  short* gxe    = (short*)take((size_t)4096 * 3072 * 2);
  float* hf     = (float*)take((size_t)65536 * 4);
  unsigned int* hsp = (unsigned int*)take((size_t)65536 * 4);
  float* attn   = (float*)take((size_t)4096 * 4);
  float* ghG    = (float*)take((size_t)3072 * 64 * 4);
  unsigned int* bar = (unsigned int*)take(256 * 4);

  // prologue: conversions
  split_bf16_kernel<<<2048, 256, 0, stream>>>(ctx, (__hip_bfloat16*)ctx_hi,
                                              (__hip_bfloat16*)ctx_lo, 8388608);
  split_bf16_kernel<<<1024, 256, 0, stream>>>(Wa, (__hip_bfloat16*)Wa_hi,
                                              (__hip_bfloat16*)Wa_lo, 2097152);
  prep_weights<<<3072, 256, 0, stream>>>(Wih, Whh, bih, bhh,
      (__hip_bfloat16*)WcH, (__hip_bfloat16*)WcL, (__hip_bfloat16*)We_p,
      (__hip_bfloat16*)WhH, (__hip_bfloat16*)WhL, bih_p, bhh_p);
  emb_gather<<<4096, 256, 0, stream>>>(tgt, embt, (__hip_bfloat16*)emb_bf);
  h0_init<<<256, 256, 0, stream>>>(h0, hf, hsp, bar);

  // ctxW = ctx @ Wa^T   (split-bf16 fused 3-product, fp32 out)
  gemm_bt3<<<dim3(8, 32), 256, 0, stream>>>(ctx_hi, ctx_lo, Wa_hi, Wa_lo,
                                            ctxW, 4096, 1024, 2048);
  // ctxWc = ctx @ Wc_perm^T (split-bf16 fused 3-product, fp32 out)
  gemm_bt3<<<dim3(24, 32), 256, 0, stream>>>(ctx_hi, ctx_lo, WcH, WcL,
                                             ctxWc, 4096, 3072, 2048);
  // gxe = emb @ We_perm^T + b_ih (bf16 out; |gxe| ~ 3e-3, rounding negligible)
  gemm_bt<<<dim3(24, 32), 256, 0, stream>>>(emb_bf, We_p, nullptr,
                                            (__hip_bfloat16*)gxe, bih_p,
                                            4096, 3072, 512, FLAG_BF);

  // persistent recurrence: one cooperative dispatch, custom flag barriers
  {
    const float* ctxWb = ctxW; const float* ctxWcB = ctxWc;
    const short* WhHc = WhH;  const short* WhLc = WhL;
    const __hip_bfloat16* gxeB = (const __hip_bfloat16*)gxe;
    const float* bhhB = bhh_p;
    void* kargs[] = {
      (void*)&ctxWb, (void*)&lens, (void*)&WhHc, (void*)&WhLc,
      (void*)&ctxWcB, (void*)&gxeB, (void*)&bhhB,
      (void*)&hf, (void*)&hsp, (void*)&attn, (void*)&ghG, (void*)&bar,
      (void*)&out
    };
    hipLaunchCooperativeKernel((void*)recurrence_kernel, dim3(256), dim3(512),
                               kargs, 0, stream);
  }
}

// Round 9
// 2283.860 us; speedup vs baseline: 1.5324x; 1.2398x over previous
//
#include <hip/hip_runtime.h>
#include <hip/hip_bf16.h>

// DecoderRNNsearch on MI355X — round 10 (resubmit; r8 bench never acquired a
// GPU). Proven r7 multi-launch structure (2414 us) + two counter-driven fixes:
//   (1) gemm_bt / gemm_bt3: LDS XOR-swizzle (T21: pre-swizzled GLOBAL source
//       + swizzled ds_read). r7 counters: 1.26e7 bank-conflict cycles at
//       MfmaUtil 48% — the 4-way-conflicted ds_read_b128 service groups were
//       the K-loop critical path (~4 extra cyc/read).
//       colblock' = colblock ^ ((row>>1)&3) -> disjoint 32-bank coverage.
//   (2) gate_kernel: 512 blocks (bc 8-way, 8 batches each) x 512 thr,
//       compacted l-list split 4 ways (was 2) + LDS combine — halves the
//       latency-bound gather chain, 16 waves/CU.
// Numerics identical class to r7 (fp32/split-bf16 only in the loop; the
// 4-way sum reorder is the same fp32-rounding class that passed 4x).

using short8 = __attribute__((ext_vector_type(8))) short;
using f32x4  = __attribute__((ext_vector_type(4))) float;

#define FLAG_ACC 1
#define FLAG_BF  2

__device__ __forceinline__ void gld16(const void* g, void* l) {
  __builtin_amdgcn_global_load_lds(
      (const __attribute__((address_space(1))) unsigned int*)g,
      (__attribute__((address_space(3))) unsigned int*)l, 16, 0, 0);
}

// ---------------- conversion / prep kernels ----------------

__global__ __launch_bounds__(256) void split_bf16_kernel(
    const float* __restrict__ x, __hip_bfloat16* __restrict__ hi,
    __hip_bfloat16* __restrict__ lo, int n)
{
  int i = blockIdx.x * blockDim.x + threadIdx.x;
  int stride = gridDim.x * blockDim.x;
  for (; i < n; i += stride) {
    float v = x[i];
    __hip_bfloat16 h = __float2bfloat16(v);
    hi[i] = h;
    lo[i] = __float2bfloat16(v - __bfloat162float(h));
  }
}

// permute rows j' = 3u+g  <-  source row g*1024+u ; split to bf16 hi/lo
__global__ __launch_bounds__(256) void prep_weights(
    const float* __restrict__ Wih, const float* __restrict__ Whh,
    const float* __restrict__ bih, const float* __restrict__ bhh,
    __hip_bfloat16* __restrict__ WcH, __hip_bfloat16* __restrict__ WcL,
    __hip_bfloat16* __restrict__ We,
    __hip_bfloat16* __restrict__ WhH, __hip_bfloat16* __restrict__ WhL,
    float* __restrict__ bihp, float* __restrict__ bhhp)
{
  const int jp = blockIdx.x;           // 0..3071
  const int u = jp / 3, g = jp - 3 * u;
  const int src = g * 1024 + u;
  for (int c = threadIdx.x; c < 2048; c += 256) {
    float v = Wih[(size_t)src * 2560 + 512 + c];
    __hip_bfloat16 h = __float2bfloat16(v);
    WcH[(size_t)jp * 2048 + c] = h;
    WcL[(size_t)jp * 2048 + c] = __float2bfloat16(v - __bfloat162float(h));
  }
  for (int c = threadIdx.x; c < 512; c += 256)
    We[(size_t)jp * 512 + c] = __float2bfloat16(Wih[(size_t)src * 2560 + c]);
  for (int c = threadIdx.x; c < 1024; c += 256) {
    float v = Whh[(size_t)src * 1024 + c];
    __hip_bfloat16 h = __float2bfloat16(v);
    WhH[(size_t)jp * 1024 + c] = h;
    WhL[(size_t)jp * 1024 + c] = __float2bfloat16(v - __bfloat162float(h));
  }
  if (threadIdx.x == 0) { bihp[jp] = bih[src]; bhhp[jp] = bhh[src]; }
}

__global__ __launch_bounds__(256) void emb_gather(
    const int* __restrict__ tgt, const float* __restrict__ table,
    __hip_bfloat16* __restrict__ outb)
{
  const int row = blockIdx.x;          // b*64+t, 0..4095
  const int v = tgt[row];
  for (int c = threadIdx.x; c < 512; c += 256)
    outb[(size_t)row * 512 + c] = __float2bfloat16(table[(size_t)v * 512 + c]);
}

__global__ __launch_bounds__(256) void h0_init(
    const float* __restrict__ h0, float* __restrict__ hf,
    __hip_bfloat16* __restrict__ hhi, __hip_bfloat16* __restrict__ hlo)
{
  const int i = blockIdx.x * 256 + threadIdx.x;   // grid 256 -> 65536
  float v = h0[i];
  hf[i] = v;
  __hip_bfloat16 h = __float2bfloat16(v);
  hhi[i] = h;
  hlo[i] = __float2bfloat16(v - __bfloat162float(h));
}

// ---------------- bf16 GEMM  C[M,N] = A[M,K] @ B[N,K]^T (single pass) -------
// 128x128 tile, 4 waves, BK=32, global_load_lds staging.
// LDS layout XOR-swizzled: slot (row, cb) holds global colblock cb^((row>>1)&3).
// Write side: gld16 dest is linear (lane*16B), so the GLOBAL source address is
// pre-swizzled; read side applies the same XOR. Service groups become
// disjoint-bank (conflict-free).

__global__ __launch_bounds__(256) void gemm_bt(
    const short* __restrict__ A, const short* __restrict__ B,
    float* __restrict__ Cf, __hip_bfloat16* __restrict__ Cb,
    const float* __restrict__ bias, int M, int N, int K, int flags)
{
  __shared__ __align__(16) short As[128 * 32];
  __shared__ __align__(16) short Bs[128 * 32];
  const int tid = threadIdx.x, lane = tid & 63, w = tid >> 6;
  const int m0 = blockIdx.y * 128, n0 = blockIdx.x * 128;
  const int wm = (w >> 1) * 64, wn = (w & 1) * 64;
  const int srow = lane >> 2;
  const int scol = (((lane & 3) ^ ((lane >> 3) & 3)) * 8);   // pre-swizzled src
  f32x4 zero = {0.f, 0.f, 0.f, 0.f};
  f32x4 acc[4][4];
#pragma unroll
  for (int i = 0; i < 4; ++i)
#pragma unroll
    for (int j = 0; j < 4; ++j) acc[i][j] = zero;

  for (int k0 = 0; k0 < K; k0 += 32) {
    __syncthreads();
#pragma unroll
    for (int s = 0; s < 2; ++s) {
      const int chunk = w * 2 + s;
      const int r = chunk * 16 + srow;
      gld16(A + (size_t)(m0 + r) * K + k0 + scol, As + chunk * 512);
      gld16(B + (size_t)(n0 + r) * K + k0 + scol, Bs + chunk * 512);
    }
    __syncthreads();
    const int fm = lane & 15, fq = lane >> 4;
    const int cbs = (fq ^ ((fm >> 1) & 3)) * 8;              // swizzled read
    short8 af[4], bq[4];
#pragma unroll
    for (int i = 0; i < 4; ++i)
      af[i] = *(const short8*)(As + (wm + i * 16 + fm) * 32 + cbs);
#pragma unroll
    for (int j = 0; j < 4; ++j)
      bq[j] = *(const short8*)(Bs + (wn + j * 16 + fm) * 32 + cbs);
#pragma unroll
    for (int i = 0; i < 4; ++i)
#pragma unroll
      for (int j = 0; j < 4; ++j)
        acc[i][j] = __builtin_amdgcn_mfma_f32_16x16x32_bf16(af[i], bq[j], acc[i][j], 0, 0, 0);
  }

  const int cn = lane & 15, cq = (lane >> 4) * 4;
#pragma unroll
  for (int i = 0; i < 4; ++i)
#pragma unroll
    for (int j = 0; j < 4; ++j)
#pragma unroll
      for (int r = 0; r < 4; ++r) {
        const int m = m0 + wm + i * 16 + cq + r;
        const int n = n0 + wn + j * 16 + cn;
        float v = acc[i][j][r];
        if (flags & FLAG_ACC) v += Cf[(size_t)m * N + n];
        if (bias) v += bias[n];
        if (flags & FLAG_BF) Cb[(size_t)m * N + n] = __float2bfloat16(v);
        else                 Cf[(size_t)m * N + n] = v;
      }
}

// ---------------- fused split-bf16 triple GEMM --------------------------------
// C = AH@BH^T + AL@BH^T + AH@BL^T  (effective-fp32 product), one staging pass.
// Same XOR-swizzled LDS layout as gemm_bt.

__global__ __launch_bounds__(256) void gemm_bt3(
    const short* __restrict__ AH, const short* __restrict__ AL,
    const short* __restrict__ BH, const short* __restrict__ BL,
    float* __restrict__ Cf, int M, int N, int K)
{
  __shared__ __align__(16) short AsH[128 * 32];
  __shared__ __align__(16) short AsL[128 * 32];
  __shared__ __align__(16) short BsH[128 * 32];
  __shared__ __align__(16) short BsL[128 * 32];
  const int tid = threadIdx.x, lane = tid & 63, w = tid >> 6;
  const int m0 = blockIdx.y * 128, n0 = blockIdx.x * 128;
  const int wm = (w >> 1) * 64, wn = (w & 1) * 64;
  const int srow = lane >> 2;
  const int scol = (((lane & 3) ^ ((lane >> 3) & 3)) * 8);   // pre-swizzled src
  f32x4 zero = {0.f, 0.f, 0.f, 0.f};
  f32x4 acc[4][4];
#pragma unroll
  for (int i = 0; i < 4; ++i)
#pragma unroll
    for (int j = 0; j < 4; ++j) acc[i][j] = zero;

  for (int k0 = 0; k0 < K; k0 += 32) {
    __syncthreads();
#pragma unroll
    for (int s = 0; s < 2; ++s) {
      const int chunk = w * 2 + s;
      const int r = chunk * 16 + srow;
      const size_t ao = (size_t)(m0 + r) * K + k0 + scol;
      const size_t bo = (size_t)(n0 + r) * K + k0 + scol;
      gld16(AH + ao, AsH + chunk * 512);
      gld16(AL + ao, AsL + chunk * 512);
      gld16(BH + bo, BsH + chunk * 512);
      gld16(BL + bo, BsL + chunk * 512);
    }
    __syncthreads();
    const int fm = lane & 15, fq = lane >> 4;
    const int cbs = (fq ^ ((fm >> 1) & 3)) * 8;              // swizzled read
    short8 ah[4], al[4], bh[4], bl[4];
#pragma unroll
    for (int i = 0; i < 4; ++i) {
      const int off = (wm + i * 16 + fm) * 32 + cbs;
      ah[i] = *(const short8*)(AsH + off);
      al[i] = *(const short8*)(AsL + off);
    }
#pragma unroll
    for (int j = 0; j < 4; ++j) {
      const int off = (wn + j * 16 + fm) * 32 + cbs;
      bh[j] = *(const short8*)(BsH + off);
      bl[j] = *(const short8*)(BsL + off);
    }
#pragma unroll
    for (int i = 0; i < 4; ++i)
#pragma unroll
      for (int j = 0; j < 4; ++j) {
        acc[i][j] = __builtin_amdgcn_mfma_f32_16x16x32_bf16(ah[i], bh[j], acc[i][j], 0, 0, 0);
        acc[i][j] = __builtin_amdgcn_mfma_f32_16x16x32_bf16(al[i], bh[j], acc[i][j], 0, 0, 0);
        acc[i][j] = __builtin_amdgcn_mfma_f32_16x16x32_bf16(ah[i], bl[j], acc[i][j], 0, 0, 0);
      }
  }

  const int cn = lane & 15, cq = (lane >> 4) * 4;
#pragma unroll
  for (int i = 0; i < 4; ++i)
#pragma unroll
    for (int j = 0; j < 4; ++j)
#pragma unroll
      for (int r = 0; r < 4; ++r) {
        const int m = m0 + wm + i * 16 + cq + r;
        const int n = n0 + wn + j * 16 + cn;
        Cf[(size_t)m * N + n] = acc[i][j][r];
      }
}

// ---------------- per-step kernel A: attn (blk 0-63) + gh (blk 64-255) -------

__global__ __launch_bounds__(256) void step_a(
    const float* __restrict__ hf, const float* __restrict__ ctxW,
    const int* __restrict__ lens, float* __restrict__ attn,
    const short* __restrict__ hhi, const short* __restrict__ hlo,
    const short* __restrict__ WhH, const short* __restrict__ WhL,
    float* __restrict__ ghG)
{
  const int tid = threadIdx.x;
  if (blockIdx.x < 64) {
    // ---- attention scores + masked softmax for batch b (verified r4) ----
    __shared__ float hs[1024];
    __shared__ float part[256];
    const int b = blockIdx.x;
    const int len = lens[b];
    ((float4*)hs)[tid] = ((const float4*)(hf + b * 1024))[tid];
    __syncthreads();
    const int l = tid >> 2, q = tid & 3;
    float sx = 0.f, sy = 0.f, sz = 0.f, sw = 0.f;
    if (l < len) {
      const float4* row = (const float4*)(ctxW + ((size_t)(b * 64 + l)) * 1024 + q * 256);
      const float4* hh = (const float4*)(hs + q * 256);
#pragma unroll 8
      for (int i = 0; i < 64; ++i) {
        float4 a = row[i], c = hh[i];
        sx += a.x * c.x; sy += a.y * c.y; sz += a.z * c.z; sw += a.w * c.w;
      }
    }
    part[tid] = (sx + sy) + (sz + sw);
    __syncthreads();
    if (tid < 64) {   // exactly wave 0; tid == context position
      float sc = part[tid * 4] + part[tid * 4 + 1] + part[tid * 4 + 2] + part[tid * 4 + 3];
      if (tid >= len) sc = -1e9f;
      float m = sc;
#pragma unroll
      for (int off = 32; off > 0; off >>= 1) m = fmaxf(m, __shfl_xor(m, off));
      float e = __expf(sc - m);
      float sum = e;
#pragma unroll
      for (int off = 32; off > 0; off >>= 1) sum += __shfl_xor(sum, off);
      attn[b * 64 + tid] = e / sum;
    }
  } else {
    // ---- gh = Whh_slice @ h, 16 rows/block (verified r5) ----
    const int j0 = (blockIdx.x - 64) * 16;
    const int lane = tid & 63, w = tid >> 6;
    const int fm = lane & 15, fq = lane >> 4;
    f32x4 acc = {0.f, 0.f, 0.f, 0.f};
    const short* ah = hhi + (w * 16 + fm) * 1024 + fq * 8;   // batches w*16..+15
    const short* al = hlo + (w * 16 + fm) * 1024 + fq * 8;
    const short* bh = WhH + (size_t)(j0 + fm) * 1024 + fq * 8;
    const short* bl = WhL + (size_t)(j0 + fm) * 1024 + fq * 8;
#pragma unroll 4
    for (int k0 = 0; k0 < 1024; k0 += 32) {
      short8 aH = *(const short8*)(ah + k0);
      short8 aL = *(const short8*)(al + k0);
      short8 b0 = *(const short8*)(bh + k0);
      short8 c0 = *(const short8*)(bl + k0);
      acc = __builtin_amdgcn_mfma_f32_16x16x32_bf16(aH, b0, acc, 0, 0, 0);
      acc = __builtin_amdgcn_mfma_f32_16x16x32_bf16(aL, b0, acc, 0, 0, 0);
      acc = __builtin_amdgcn_mfma_f32_16x16x32_bf16(aH, c0, acc, 0, 0, 0);
    }
    // C layout: batch = w*16 + fq*4 + r, j-row = fm  -> ghG[j'][b]
    const int mb = w * 16 + fq * 4;
    *(f32x4*)(ghG + (size_t)(j0 + fm) * 64 + mb) = acc;
  }
}

// ---------------- per-step kernel B: gates ------------------------------------
// grid 512 = (jc 0..63) x (bc 0..7), 512 threads. Block: 16 units (48 j') x
// 8 batches. Compacted l-list split across 4 thread-quarters (LDS combine):
// quarter q = tid>>7 owns [q*n/4, (q+1)*n/4). fp32 ctxWc, nontemporal loads.

__global__ __launch_bounds__(512) void gate_kernel(
    const float* __restrict__ attn, const int* __restrict__ lens,
    const float* __restrict__ ghG, const float* __restrict__ ctxWc,
    const __hip_bfloat16* __restrict__ gxe, const float* __restrict__ bhhp,
    float* __restrict__ hf, short* __restrict__ hhi, short* __restrict__ hlo,
    float* __restrict__ out, int t)
{
  const int jc = blockIdx.x & 63, bc = blockIdx.x >> 6;     // bc 0..7
  const int j0 = jc * 48, b0 = bc * 8;
  __shared__ float ghs[48 * 9];       // [j_local][bb], stride 9 (bank spread)
  __shared__ float wv[8][64];
  __shared__ short lidx[8][64];
  __shared__ int   cnt[8];
  __shared__ float ps0[384], ps1[384], ps2[384];
  const int tid = threadIdx.x;
  if (tid < 8) cnt[tid] = 0;
  if (tid < 384) {
    const int row = tid >> 3, col = tid & 7;
    ghs[row * 9 + col] = ghG[(size_t)(j0 + row) * 64 + b0 + col];
  }
  __syncthreads();
  if (tid < 128) {
    const int bb = tid >> 4, l4 = (tid & 15) * 4;
    const int b = b0 + bb, len = lens[b];
#pragma unroll
    for (int k = 0; k < 4; ++k) {
      const int l = l4 + k;
      const float wl = attn[b * 64 + l];
      if (l < len && wl >= 1e-8f) {
        const int pos = atomicAdd(&cnt[bb], 1);
        lidx[bb][pos] = (short)l;
        wv[bb][pos] = wl;
      }
    }
  }
  __syncthreads();

  const int q = tid >> 7, tl = tid & 127;
  const int bb = tl >> 4, jg = tl & 15;
  const int b = b0 + bb;
  const int n = cnt[bb];
  const int ibeg = (q * n) >> 2;
  const int iend = ((q + 1) * n) >> 2;
  float g0 = 0.f, g1 = 0.f, g2 = 0.f;
  const float* base = ctxWc + (size_t)(b * 64) * 3072 + j0 + jg * 3;
  int i = ibeg;
  for (; i + 3 < iend; i += 4) {          // 4 outstanding scattered loads
    const float w0 = wv[bb][i],     w1 = wv[bb][i + 1];
    const float w2 = wv[bb][i + 2], w3 = wv[bb][i + 3];
    const float* p0 = base + (size_t)lidx[bb][i] * 3072;
    const float* p1 = base + (size_t)lidx[bb][i + 1] * 3072;
    const float* p2 = base + (size_t)lidx[bb][i + 2] * 3072;
    const float* p3 = base + (size_t)lidx[bb][i + 3] * 3072;
    const float a0 = __builtin_nontemporal_load(p0);
    const float a1 = __builtin_nontemporal_load(p0 + 1);
    const float a2 = __builtin_nontemporal_load(p0 + 2);
    const float b0v = __builtin_nontemporal_load(p1);
    const float b1v = __builtin_nontemporal_load(p1 + 1);
    const float b2v = __builtin_nontemporal_load(p1 + 2);
    const float c0 = __builtin_nontemporal_load(p2);
    const float c1 = __builtin_nontemporal_load(p2 + 1);
    const float c2 = __builtin_nontemporal_load(p2 + 2);
    const float d0 = __builtin_nontemporal_load(p3);
    const float d1 = __builtin_nontemporal_load(p3 + 1);
    const float d2 = __builtin_nontemporal_load(p3 + 2);
    g0 += (w0 * a0 + w1 * b0v) + (w2 * c0 + w3 * d0);
    g1 += (w0 * a1 + w1 * b1v) + (w2 * c1 + w3 * d1);
    g2 += (w0 * a2 + w1 * b2v) + (w2 * c2 + w3 * d2);
  }
  for (; i < iend; ++i) {
    const float wa = wv[bb][i];
    const float* pa = base + (size_t)lidx[bb][i] * 3072;
    g0 += wa * __builtin_nontemporal_load(pa);
    g1 += wa * __builtin_nontemporal_load(pa + 1);
    g2 += wa * __builtin_nontemporal_load(pa + 2);
  }
  if (q) {
    const int o = (q - 1) * 128 + tl;
    ps0[o] = g0; ps1[o] = g1; ps2[o] = g2;
  }
  __syncthreads();
  if (q == 0) {
    g0 += (ps0[tl] + ps0[128 + tl]) + ps0[256 + tl];
    g1 += (ps1[tl] + ps1[128 + tl]) + ps1[256 + tl];
    g2 += (ps2[tl] + ps2[128 + tl]) + ps2[256 + tl];

    const int jp = j0 + jg * 3;
    const __hip_bfloat16* ge = gxe + (size_t)(b * 64 + t) * 3072 + jp;
    const float gxr = g0 + __bfloat162float(ge[0]);
    const float gxz = g1 + __bfloat162float(ge[1]);
    const float gxn = g2 + __bfloat162float(ge[2]);
    const float ghr = ghs[(jg * 3 + 0) * 9 + bb] + bhhp[jp + 0];
    const float ghz = ghs[(jg * 3 + 1) * 9 + bb] + bhhp[jp + 1];
    const float ghn = ghs[(jg * 3 + 2) * 9 + bb] + bhhp[jp + 2];
    const float rr = 1.f / (1.f + __expf(-(gxr + ghr)));
    const float zz = 1.f / (1.f + __expf(-(gxz + ghz)));
    const float nn = tanhf(gxn + rr * ghn);
    const int u = jc * 16 + jg;
    const float hold = hf[b * 1024 + u];
    const float hn = (1.f - zz) * nn + zz * hold;
    out[(size_t)(b * 64 + t) * 1024 + u] = hn;
    hf[b * 1024 + u] = hn;
    __hip_bfloat16 hh = __float2bfloat16(hn);
    hhi[b * 1024 + u] = *reinterpret_cast<short*>(&hh);
    __hip_bfloat16 hl = __float2bfloat16(hn - __bfloat162float(hh));
    hlo[b * 1024 + u] = *reinterpret_cast<short*>(&hl);
    if (t == 63) out[(size_t)64 * 64 * 1024 + b * 1024 + u] = hn;
  }
}

// ---------------- launcher ----------------

extern "C" void kernel_launch(void* const* d_in, const int* in_sizes, int n_in,
                              void* d_out, int out_size, void* d_ws, size_t ws_size,
                              hipStream_t stream)
{
  const int*   tgt  = (const int*)  d_in[0];
  const float* ctx  = (const float*)d_in[1];
  const float* h0   = (const float*)d_in[2];
  const int*   lens = (const int*)  d_in[3];
  const float* embt = (const float*)d_in[4];
  const float* Wa   = (const float*)d_in[5];
  const float* Wih  = (const float*)d_in[6];
  const float* Whh  = (const float*)d_in[7];
  const float* bih  = (const float*)d_in[8];
  const float* bhh  = (const float*)d_in[9];
  float* out = (float*)d_out;

  char* p = (char*)d_ws;
  auto take = [&](size_t bytes) {
    char* q = p;
    p += (bytes + 255) & ~(size_t)255;
    return q;
  };
  short* ctx_hi = (short*)take((size_t)8388608 * 2);
  short* ctx_lo = (short*)take((size_t)8388608 * 2);
  short* Wa_hi  = (short*)take((size_t)2097152 * 2);
  short* Wa_lo  = (short*)take((size_t)2097152 * 2);
  short* WcH    = (short*)take((size_t)3072 * 2048 * 2);
  short* WcL    = (short*)take((size_t)3072 * 2048 * 2);
  short* We_p   = (short*)take((size_t)3072 * 512 * 2);
  short* WhH    = (short*)take((size_t)3072 * 1024 * 2);
  short* WhL    = (short*)take((size_t)3072 * 1024 * 2);
  float* bih_p  = (float*)take(3072 * 4);
  float* bhh_p  = (float*)take(3072 * 4);
  short* emb_bf = (short*)take((size_t)4096 * 512 * 2);
  float* ctxW   = (float*)take((size_t)4096 * 1024 * 4);
  float* ctxWc  = (float*)take((size_t)4096 * 3072 * 4);
  short* gxe    = (short*)take((size_t)4096 * 3072 * 2);
  float* hf     = (float*)take((size_t)65536 * 4);
  short* hhi    = (short*)take((size_t)65536 * 2);
  short* hlo    = (short*)take((size_t)65536 * 2);
  float* attn   = (float*)take((size_t)4096 * 4);
  float* ghG    = (float*)take((size_t)3072 * 64 * 4);

  // prologue: conversions
  split_bf16_kernel<<<2048, 256, 0, stream>>>(ctx, (__hip_bfloat16*)ctx_hi,
                                              (__hip_bfloat16*)ctx_lo, 8388608);
  split_bf16_kernel<<<1024, 256, 0, stream>>>(Wa, (__hip_bfloat16*)Wa_hi,
                                              (__hip_bfloat16*)Wa_lo, 2097152);
  prep_weights<<<3072, 256, 0, stream>>>(Wih, Whh, bih, bhh,
      (__hip_bfloat16*)WcH, (__hip_bfloat16*)WcL, (__hip_bfloat16*)We_p,
      (__hip_bfloat16*)WhH, (__hip_bfloat16*)WhL, bih_p, bhh_p);
  emb_gather<<<4096, 256, 0, stream>>>(tgt, embt, (__hip_bfloat16*)emb_bf);
  h0_init<<<256, 256, 0, stream>>>(h0, hf, (__hip_bfloat16*)hhi,
                                   (__hip_bfloat16*)hlo);

  // ctxW = ctx @ Wa^T   (split-bf16 fused 3-product, fp32 out)
  gemm_bt3<<<dim3(8, 32), 256, 0, stream>>>(ctx_hi, ctx_lo, Wa_hi, Wa_lo,
                                            ctxW, 4096, 1024, 2048);
  // ctxWc = ctx @ Wc_perm^T (split-bf16 fused 3-product, fp32 out)
  gemm_bt3<<<dim3(24, 32), 256, 0, stream>>>(ctx_hi, ctx_lo, WcH, WcL,
                                             ctxWc, 4096, 3072, 2048);
  // gxe = emb @ We_perm^T + b_ih (bf16 out; |gxe| ~ 3e-3, rounding negligible)
  gemm_bt<<<dim3(24, 32), 256, 0, stream>>>(emb_bf, We_p, nullptr,
                                            (__hip_bfloat16*)gxe, bih_p,
                                            4096, 3072, 512, FLAG_BF);

  // sequential recurrence: 2 launches per step
  for (int t = 0; t < 64; ++t) {
    step_a<<<256, 256, 0, stream>>>(hf, ctxW, lens, attn,
                                    hhi, hlo, WhH, WhL, ghG);
    gate_kernel<<<512, 512, 0, stream>>>(attn, lens, ghG, ctxWc,
        (const __hip_bfloat16*)gxe, bhh_p, hf, hhi, hlo, out, t);
  }
}